// Round 1
// baseline (764.650 us; speedup 1.0000x reference)
//
#include <hip/hip_runtime.h>

// SimpleRNN: x(256,2048,8) f32, h(1,256,128), W_ih(128,8), W_hh(128,128),
// b_ih(128), b_hh(128), W_head(1,128), b_head(1)
// out = [pred(256,1) | last_step_features(256,128) | h_n(1,256,128)]  (f32)

#define BB 256
#define TT 2048
#define II 8
#define HH 128
#define THREADS 512

__launch_bounds__(THREADS, 1)
__global__ void rnn_fused_kernel(const float* __restrict__ x,
                                 const float* __restrict__ h0,
                                 const float* __restrict__ W_ih,
                                 const float* __restrict__ W_hh,
                                 const float* __restrict__ b_ih,
                                 const float* __restrict__ b_hh,
                                 const float* __restrict__ W_head,
                                 const float* __restrict__ b_head,
                                 float* __restrict__ out)
{
    __shared__ float h_lds[HH];
    __shared__ float part[THREADS];
    __shared__ float x_stage[2][16 * II];   // 16 timesteps per buffer

    const int b   = blockIdx.x;
    const int tid = threadIdx.x;
    const int j   = tid & (HH - 1);   // output index 0..127
    const int kc  = tid >> 7;         // k-chunk 0..3 (32 k's each)

    // --- W_hh chunk in registers: w4[m] = W_hh[j][kc*32 + 4m .. 4m+3] ---
    float4 w4[8];
    {
        const float4* wr = (const float4*)(W_hh + j * HH + kc * 32);
        #pragma unroll
        for (int m = 0; m < 8; ++m) w4[m] = wr[m];
    }
    // W_ih row j + combined bias (used by tid<128 in phase 2)
    const float4 wi0 = ((const float4*)(W_ih + j * II))[0];
    const float4 wi1 = ((const float4*)(W_ih + j * II))[1];
    const float bias = b_ih[j] + b_hh[j];

    const float* xg = x + (size_t)b * TT * II;

    if (tid < HH) {
        h_lds[j] = h0[b * HH + j];
        x_stage[0][tid] = xg[tid];    // x for steps 0..15 (128 floats)
    }
    __syncthreads();

    float xpre = 0.0f;
    for (int t = 0; t < TT; ++t) {
        // ---- phase 1: partial dot products (all 512 threads) ----
        float acc = 0.0f;
        #pragma unroll
        for (int m = 0; m < 8; ++m) {
            float4 hv = *(const float4*)&h_lds[kc * 32 + m * 4];  // broadcast
            acc = fmaf(hv.x, w4[m].x, acc);
            acc = fmaf(hv.y, w4[m].y, acc);
            acc = fmaf(hv.z, w4[m].z, acc);
            acc = fmaf(hv.w, w4[m].w, acc);
        }
        part[tid] = acc;
        __syncthreads();

        // ---- phase 2: reduce + x-proj + tanh (threads 0..127) ----
        if (tid < HH) {
            const int tin = t & 15;
            if (tin == 0) {   // issue prefetch for the next 16-step chunk
                const int tn = t + 16;
                xpre = (tn < TT) ? xg[tn * II + tid] : 0.0f;  // coalesced
            }
            float s = part[j] + part[j + HH] + part[j + 2 * HH] + part[j + 3 * HH] + bias;
            const float* xt = &x_stage[(t >> 4) & 1][tin * II];
            s = fmaf(xt[0], wi0.x, s);
            s = fmaf(xt[1], wi0.y, s);
            s = fmaf(xt[2], wi0.z, s);
            s = fmaf(xt[3], wi0.w, s);
            s = fmaf(xt[4], wi1.x, s);
            s = fmaf(xt[5], wi1.y, s);
            s = fmaf(xt[6], wi1.z, s);
            s = fmaf(xt[7], wi1.w, s);
            // tanh(s) = 1 - 2/(exp(2s)+1), native exp + rcp (~1e-7 abs err)
            float e  = __expf(2.0f * s);
            float hn = 1.0f - 2.0f * __builtin_amdgcn_rcpf(e + 1.0f);
            h_lds[j] = hn;
            if (tin == 15) x_stage[((t >> 4) + 1) & 1][tid] = xpre;
        }
        __syncthreads();
    }

    // ---- epilogue: outputs ----
    if (tid < HH) {
        const float hl = h_lds[j];
        out[BB + b * HH + j]           = hl;   // last_step_features
        out[BB + BB * HH + b * HH + j] = hl;   // h_n
        part[j] = hl * W_head[j];
    }
    __syncthreads();
    if (tid == 0) {
        float s = 0.0f;
        for (int k = 0; k < HH; ++k) s += part[k];
        out[b] = s + b_head[0];
    }
}

extern "C" void kernel_launch(void* const* d_in, const int* in_sizes, int n_in,
                              void* d_out, int out_size, void* d_ws, size_t ws_size,
                              hipStream_t stream) {
    const float* x      = (const float*)d_in[0];
    const float* h0     = (const float*)d_in[1];
    const float* W_ih   = (const float*)d_in[2];
    const float* W_hh   = (const float*)d_in[3];
    const float* b_ih   = (const float*)d_in[4];
    const float* b_hh   = (const float*)d_in[5];
    const float* W_head = (const float*)d_in[6];
    const float* b_head = (const float*)d_in[7];
    float* out = (float*)d_out;

    hipLaunchKernelGGL(rnn_fused_kernel, dim3(BB), dim3(THREADS), 0, stream,
                       x, h0, W_ih, W_hh, b_ih, b_hh, W_head, b_head, out);
}

// Round 3
// 751.260 us; speedup vs baseline: 1.0178x; 1.0178x over previous
//
#include <hip/hip_runtime.h>

// SimpleRNN: x(256,2048,8) f32, h(1,256,128), W_ih(128,8), W_hh(128,128),
// b_ih(128), b_hh(128), W_head(1,128), b_head(1)
// out = [pred(256) | last_step_features(256,128) | h_n(256,128)]  (f32)
//
// One block per batch row (256 blocks = 256 CUs). 512 threads = 8 waves.
// Lane mapping: lane = 4*jg + kc  (jg=0..15, kc=0..3); j = wave*16 + jg.
// Each thread holds W_hh[j][kc*32 .. kc*32+31] in 8 float4 registers.
// Per step: 32 FMA vs broadcast h (LDS), quad_perm DPP butterfly reduce
// (no barrier), tanh, masked h-write to the OTHER h buffer, ONE barrier.

#define BB 256
#define TT 2048
#define II 8
#define HH 128
#define THREADS 512

__device__ __forceinline__ float quad_sum(float x) {
    // butterfly over each aligned group of 4 lanes via DPP quad_perm
    int xi = __builtin_bit_cast(int, x);
    int y1 = __builtin_amdgcn_update_dpp(0, xi, 0xB1, 0xF, 0xF, true); // [1,0,3,2] xor1
    float s1 = x + __builtin_bit_cast(float, y1);
    int s1i = __builtin_bit_cast(int, s1);
    int y2 = __builtin_amdgcn_update_dpp(0, s1i, 0x4E, 0xF, 0xF, true); // [2,3,0,1] xor2
    return s1 + __builtin_bit_cast(float, y2);
}

__launch_bounds__(THREADS, 1)
__global__ void rnn_fused2_kernel(const float* __restrict__ x,
                                  const float* __restrict__ h0,
                                  const float* __restrict__ W_ih,
                                  const float* __restrict__ W_hh,
                                  const float* __restrict__ b_ih,
                                  const float* __restrict__ b_hh,
                                  const float* __restrict__ W_head,
                                  const float* __restrict__ b_head,
                                  float* __restrict__ out)
{
    __shared__ __align__(16) float h_lds[2][HH];     // double-buffered hidden state
    __shared__ __align__(16) float x_flat[2 * 16 * II]; // 2 x 16-step x stage (flat, 256 f)

    const int b    = blockIdx.x;
    const int tid  = threadIdx.x;
    const int lane = tid & 63;
    const int w    = tid >> 6;        // wave 0..7
    const int jg   = lane >> 2;       // 0..15
    const int kc   = lane & 3;        // 0..3
    const int j    = w * 16 + jg;     // output index 0..127

    // W_hh chunk in registers, ROTATED so that simultaneous reads of h by the
    // 4 kc groups hit disjoint bank quartets: slot i holds m=(i+2kc)&7.
    float4 w4[8];
    {
        const float4* wr4 = (const float4*)(W_hh + j * HH + kc * 32);
        #pragma unroll
        for (int i = 0; i < 8; ++i) w4[i] = wr4[(i + 2 * kc) & 7];
    }
    // x-projection: this lane covers inputs {2kc, 2kc+1}; bias split 4 ways.
    const float2 wi2   = ((const float2*)(W_ih + j * II))[kc];
    const float  biasq = 0.25f * (b_ih[j] + b_hh[j]);

    const float* xg = x + (size_t)b * TT * II;

    if (tid < HH) {
        h_lds[0][tid] = h0[b * HH + tid];
        x_flat[tid]   = xg[tid];          // x for steps 0..15
    }
    __syncthreads();

    float xpre = 0.0f;
    int xoff = 2 * kc;                    // rolling index into x_flat (mod 256)

    for (int tb = 0; tb < TT; tb += 2) {
        #pragma unroll
        for (int half = 0; half < 2; ++half) {
            const int t  = tb + half;
            const int RB = half;          // read buffer (compile-time)

            // x prefetch (waves 0-1 only; branch is wave-uniform)
            if (tid < HH) {
                if ((t & 15) == 0) {
                    const int tn = t + 16;
                    xpre = (tn < TT) ? xg[tn * II + tid] : 0.0f;  // coalesced
                }
            }

            // accumulate: bias/4 + this lane's 2 x-FMAs + 32 h-FMAs
            const float2 xv = *(const float2*)&x_flat[xoff];
            float a0 = fmaf(xv.x, wi2.x, biasq);
            a0 = fmaf(xv.y, wi2.y, a0);
            float a1 = 0.0f, a2 = 0.0f, a3 = 0.0f;
            #pragma unroll
            for (int i = 0; i < 8; i += 4) {
                const int r0 = (i + 0 + 2 * kc) & 7;
                const int r1 = (i + 1 + 2 * kc) & 7;
                const int r2 = (i + 2 + 2 * kc) & 7;
                const int r3 = (i + 3 + 2 * kc) & 7;
                float4 hv;
                hv = *(const float4*)&h_lds[RB][kc * 32 + r0 * 4];
                a0 = fmaf(hv.x, w4[i+0].x, a0); a0 = fmaf(hv.y, w4[i+0].y, a0);
                a0 = fmaf(hv.z, w4[i+0].z, a0); a0 = fmaf(hv.w, w4[i+0].w, a0);
                hv = *(const float4*)&h_lds[RB][kc * 32 + r1 * 4];
                a1 = fmaf(hv.x, w4[i+1].x, a1); a1 = fmaf(hv.y, w4[i+1].y, a1);
                a1 = fmaf(hv.z, w4[i+1].z, a1); a1 = fmaf(hv.w, w4[i+1].w, a1);
                hv = *(const float4*)&h_lds[RB][kc * 32 + r2 * 4];
                a2 = fmaf(hv.x, w4[i+2].x, a2); a2 = fmaf(hv.y, w4[i+2].y, a2);
                a2 = fmaf(hv.z, w4[i+2].z, a2); a2 = fmaf(hv.w, w4[i+2].w, a2);
                hv = *(const float4*)&h_lds[RB][kc * 32 + r3 * 4];
                a3 = fmaf(hv.x, w4[i+3].x, a3); a3 = fmaf(hv.y, w4[i+3].y, a3);
                a3 = fmaf(hv.z, w4[i+3].z, a3); a3 = fmaf(hv.w, w4[i+3].w, a3);
            }
            const float acc = (a0 + a1) + (a2 + a3);

            // cross-lane reduce over the 4 kc lanes (DPP, no barrier)
            const float s = quad_sum(acc);

            // tanh(s) = 1 - 2/(2^(2*log2e*s) + 1)
            const float e2 = __builtin_amdgcn_exp2f(s * 2.8853900817779268f);
            const float hn = 1.0f - 2.0f * __builtin_amdgcn_rcpf(e2 + 1.0f);

            if (kc == 0) h_lds[RB ^ 1][j] = hn;   // 16 distinct banks per wave

            if (tid < HH) {
                if ((t & 15) == 15) x_flat[(((t >> 4) + 1) & 1) * 16 * II + tid] = xpre;
            }

            xoff = (xoff + II) & (2 * 16 * II - 1);
            __syncthreads();   // ONE barrier per step
        }
    }

    // epilogue: final h is in h_lds[0] (t=2047 wrote RB^1 = 0)
    if (tid < HH) {
        const float hl = h_lds[0][tid];
        out[BB + b * HH + tid]           = hl;   // last_step_features
        out[BB + BB * HH + b * HH + tid] = hl;   // h_n
    }
    if (w == 0) {
        float s = h_lds[0][lane]      * W_head[lane]
                + h_lds[0][lane + 64] * W_head[lane + 64];
        #pragma unroll
        for (int off = 32; off > 0; off >>= 1) s += __shfl_down(s, off);
        if (lane == 0) out[b] = s + b_head[0];
    }
}

extern "C" void kernel_launch(void* const* d_in, const int* in_sizes, int n_in,
                              void* d_out, int out_size, void* d_ws, size_t ws_size,
                              hipStream_t stream) {
    const float* x      = (const float*)d_in[0];
    const float* h0     = (const float*)d_in[1];
    const float* W_ih   = (const float*)d_in[2];
    const float* W_hh   = (const float*)d_in[3];
    const float* b_ih   = (const float*)d_in[4];
    const float* b_hh   = (const float*)d_in[5];
    const float* W_head = (const float*)d_in[6];
    const float* b_head = (const float*)d_in[7];
    float* out = (float*)d_out;

    hipLaunchKernelGGL(rnn_fused2_kernel, dim3(BB), dim3(THREADS), 0, stream,
                       x, h0, W_ih, W_hh, b_ih, b_hh, W_head, b_head, out);
}

// Round 4
// 730.596 us; speedup vs baseline: 1.0466x; 1.0283x over previous
//
#include <hip/hip_runtime.h>

// SimpleRNN: x(256,2048,8) f32, h(1,256,128), W_ih(128,8), W_hh(128,128),
// b_ih(128), b_hh(128), W_head(1,128), b_head(1)
// out = [pred(256) | last_step_features(256,128) | h_n(256,128)]  (f32)
//
// One block per batch row (256 blocks = 256 CUs). 512 threads = 8 waves.
// Lane mapping: lane = 4*jg + kc  (jg=0..15, kc=0..3); j = wave*16 + jg.
// Each thread holds W_hh[j][kc*32 .. kc*32+31] in 8 float4 registers,
// PINNED via empty asm so the compiler cannot rematerialize/spill them
// (R1 post-mortem: VGPR_Count=32 proved weights were re-fetched per step).

#define BB 256
#define TT 2048
#define II 8
#define HH 128
#define THREADS 512

__device__ __forceinline__ float quad_sum(float x) {
    // butterfly over each aligned group of 4 lanes via DPP quad_perm
    int xi = __builtin_bit_cast(int, x);
    int y1 = __builtin_amdgcn_update_dpp(0, xi, 0xB1, 0xF, 0xF, true); // [1,0,3,2] xor1
    float s1 = x + __builtin_bit_cast(float, y1);
    int s1i = __builtin_bit_cast(int, s1);
    int y2 = __builtin_amdgcn_update_dpp(0, s1i, 0x4E, 0xF, 0xF, true); // [2,3,0,1] xor2
    return s1 + __builtin_bit_cast(float, y2);
}

__launch_bounds__(THREADS, 1)
__global__ void rnn_fused3_kernel(const float* __restrict__ x,
                                  const float* __restrict__ h0,
                                  const float* __restrict__ W_ih,
                                  const float* __restrict__ W_hh,
                                  const float* __restrict__ b_ih,
                                  const float* __restrict__ b_hh,
                                  const float* __restrict__ W_head,
                                  const float* __restrict__ b_head,
                                  float* __restrict__ out)
{
    __shared__ __align__(16) float h_lds[2][HH];        // double-buffered hidden state
    __shared__ __align__(16) float x_flat[2 * 16 * II]; // 2 x 16-step x stage (256 f)

    const int b    = blockIdx.x;
    const int tid  = threadIdx.x;
    const int lane = tid & 63;
    const int w    = tid >> 6;        // wave 0..7
    const int jg   = lane >> 2;       // 0..15
    const int kc   = lane & 3;        // 0..3
    const int j    = w * 16 + jg;     // output index 0..127

    // W_hh chunk in registers, ROTATED so the 4 kc groups' simultaneous
    // broadcast reads of h hit disjoint bank quartets: slot i holds m=(i+2kc)&7.
    float4 w4[8];
    {
        const float4* wr4 = (const float4*)(W_hh + j * HH + kc * 32);
        #pragma unroll
        for (int i = 0; i < 8; ++i) w4[i] = wr4[(i + 2 * kc) & 7];
    }
    // x-projection: this lane covers inputs {2kc, 2kc+1}; bias split 4 ways.
    float2 wi2   = ((const float2*)(W_ih + j * II))[kc];
    float  biasq = 0.25f * (b_ih[j] + b_hh[j]);

    // --- PIN weights in VGPRs: asm "writes" them, so the compiler can no
    // longer rematerialize from memory; they must stay live in registers. ---
    #pragma unroll
    for (int i = 0; i < 8; ++i)
        asm volatile("" : "+v"(w4[i].x), "+v"(w4[i].y), "+v"(w4[i].z), "+v"(w4[i].w));
    asm volatile("" : "+v"(wi2.x), "+v"(wi2.y), "+v"(biasq));

    const float* xg = x + (size_t)b * TT * II;

    if (tid < HH) {
        h_lds[0][tid] = h0[b * HH + tid];
        x_flat[tid]   = xg[tid];          // x for steps 0..15
    }
    __syncthreads();

    float xpre = 0.0f;
    int xoff = 2 * kc;                    // rolling index into x_flat (mod 256)

    for (int tb = 0; tb < TT; tb += 2) {
        #pragma unroll
        for (int half = 0; half < 2; ++half) {
            const int t  = tb + half;
            const int RB = half;          // read buffer (compile-time)

            // x prefetch (tid<128 only; branch is wave-uniform)
            if (tid < HH) {
                if ((t & 15) == 0) {
                    const int tn = t + 16;
                    xpre = (tn < TT) ? xg[tn * II + tid] : 0.0f;  // coalesced
                }
            }

            // accumulate: bias/4 + this lane's 2 x-FMAs + 32 h-FMAs
            const float2 xv = *(const float2*)&x_flat[xoff];
            float a0 = fmaf(xv.x, wi2.x, biasq);
            a0 = fmaf(xv.y, wi2.y, a0);
            float a1 = 0.0f, a2 = 0.0f, a3 = 0.0f;
            #pragma unroll
            for (int i = 0; i < 8; i += 4) {
                const int r0 = (i + 0 + 2 * kc) & 7;
                const int r1 = (i + 1 + 2 * kc) & 7;
                const int r2 = (i + 2 + 2 * kc) & 7;
                const int r3 = (i + 3 + 2 * kc) & 7;
                float4 hv;
                hv = *(const float4*)&h_lds[RB][kc * 32 + r0 * 4];
                a0 = fmaf(hv.x, w4[i+0].x, a0); a0 = fmaf(hv.y, w4[i+0].y, a0);
                a0 = fmaf(hv.z, w4[i+0].z, a0); a0 = fmaf(hv.w, w4[i+0].w, a0);
                hv = *(const float4*)&h_lds[RB][kc * 32 + r1 * 4];
                a1 = fmaf(hv.x, w4[i+1].x, a1); a1 = fmaf(hv.y, w4[i+1].y, a1);
                a1 = fmaf(hv.z, w4[i+1].z, a1); a1 = fmaf(hv.w, w4[i+1].w, a1);
                hv = *(const float4*)&h_lds[RB][kc * 32 + r2 * 4];
                a2 = fmaf(hv.x, w4[i+2].x, a2); a2 = fmaf(hv.y, w4[i+2].y, a2);
                a2 = fmaf(hv.z, w4[i+2].z, a2); a2 = fmaf(hv.w, w4[i+2].w, a2);
                hv = *(const float4*)&h_lds[RB][kc * 32 + r3 * 4];
                a3 = fmaf(hv.x, w4[i+3].x, a3); a3 = fmaf(hv.y, w4[i+3].y, a3);
                a3 = fmaf(hv.z, w4[i+3].z, a3); a3 = fmaf(hv.w, w4[i+3].w, a3);
            }
            const float acc = (a0 + a1) + (a2 + a3);

            // cross-lane reduce over the 4 kc lanes (DPP, no barrier)
            const float s = quad_sum(acc);

            // tanh(s) = 1 - 2/(2^(2*log2e*s) + 1)
            const float e2 = __builtin_amdgcn_exp2f(s * 2.8853900817779268f);
            const float hn = 1.0f - 2.0f * __builtin_amdgcn_rcpf(e2 + 1.0f);

            if (kc == 0) h_lds[RB ^ 1][j] = hn;   // 16 distinct banks per wave

            if (tid < HH) {
                if ((t & 15) == 15) x_flat[(((t >> 4) + 1) & 1) * 16 * II + tid] = xpre;
            }

            xoff = (xoff + II) & (2 * 16 * II - 1);
            __syncthreads();   // ONE barrier per step
        }
    }

    // epilogue: final h is in h_lds[0] (t=2047 wrote RB^1 = 0)
    if (tid < HH) {
        const float hl = h_lds[0][tid];
        out[BB + b * HH + tid]           = hl;   // last_step_features
        out[BB + BB * HH + b * HH + tid] = hl;   // h_n
    }
    if (w == 0) {
        float s = h_lds[0][lane]      * W_head[lane]
                + h_lds[0][lane + 64] * W_head[lane + 64];
        #pragma unroll
        for (int off = 32; off > 0; off >>= 1) s += __shfl_down(s, off);
        if (lane == 0) out[b] = s + b_head[0];
    }
}

extern "C" void kernel_launch(void* const* d_in, const int* in_sizes, int n_in,
                              void* d_out, int out_size, void* d_ws, size_t ws_size,
                              hipStream_t stream) {
    const float* x      = (const float*)d_in[0];
    const float* h0     = (const float*)d_in[1];
    const float* W_ih   = (const float*)d_in[2];
    const float* W_hh   = (const float*)d_in[3];
    const float* b_ih   = (const float*)d_in[4];
    const float* b_hh   = (const float*)d_in[5];
    const float* W_head = (const float*)d_in[6];
    const float* b_head = (const float*)d_in[7];
    float* out = (float*)d_out;

    hipLaunchKernelGGL(rnn_fused3_kernel, dim3(BB), dim3(THREADS), 0, stream,
                       x, h0, W_ih, W_hh, b_ih, b_hh, W_head, b_head, out);
}

// Round 5
// 648.518 us; speedup vs baseline: 1.1791x; 1.1266x over previous
//
#include <hip/hip_runtime.h>

// SimpleRNN: x(256,2048,8) f32, h(1,256,128), W_ih(128,8), W_hh(128,128),
// b_ih(128), b_hh(128), W_head(1,128), b_head(1)
// out = [pred(256) | last_step_features(256,128) | h_n(256,128)]  (f32)
//
// One block per batch row (256 blocks = 256 CUs). 512 threads = 8 waves.
// lane = 4*jg + kc (jg=0..15, kc=0..3); j = wave*16 + jg.
// Thread holds W_hh[j][kc*32..kc*32+31] as 16 f32x2 VGPR pairs, consumed by
// inline-asm v_pk_fma_f32 ("v" constraints + opaque pin => compiler cannot
// rematerialize the weight loads inside the loop; R0-R2 were secretly
// L2-BW-bound at ~45 TB/s re-fetching W_hh every step, VGPR_Count=32 proof).

typedef float f32x2 __attribute__((ext_vector_type(2)));
typedef float f32x4 __attribute__((ext_vector_type(4)));

#define BB 256
#define TT 2048
#define II 8
#define HH 128
#define THREADS 512

__device__ __forceinline__ float quad_sum(float x) {
    // butterfly over each aligned group of 4 lanes via DPP quad_perm
    int xi = __builtin_bit_cast(int, x);
    int y1 = __builtin_amdgcn_update_dpp(0, xi, 0xB1, 0xF, 0xF, true); // [1,0,3,2]
    float s1 = x + __builtin_bit_cast(float, y1);
    int s1i = __builtin_bit_cast(int, s1);
    int y2 = __builtin_amdgcn_update_dpp(0, s1i, 0x4E, 0xF, 0xF, true); // [2,3,0,1]
    return s1 + __builtin_bit_cast(float, y2);
}

__launch_bounds__(THREADS, 1)
__global__ void rnn_fused4_kernel(const float* __restrict__ x,
                                  const float* __restrict__ h0,
                                  const float* __restrict__ W_ih,
                                  const float* __restrict__ W_hh,
                                  const float* __restrict__ b_ih,
                                  const float* __restrict__ b_hh,
                                  const float* __restrict__ W_head,
                                  const float* __restrict__ b_head,
                                  float* __restrict__ out)
{
    __shared__ __align__(16) float h_lds[2][HH];        // double-buffered hidden
    __shared__ __align__(16) float x_flat[2 * 16 * II]; // 2 x 16-step x stage

    const int b    = blockIdx.x;
    const int tid  = threadIdx.x;
    const int lane = tid & 63;
    const int w    = tid >> 6;        // wave 0..7
    const int jg   = lane >> 2;       // 0..15
    const int kc   = lane & 3;        // 0..3
    const int j    = w * 16 + jg;     // output index 0..127

    // Weights as 16 f32x2. Slot i (float4 granularity) holds m=(i+2kc)&7 so
    // the 4 kc groups' simultaneous h broadcasts hit disjoint bank quartets.
    f32x2 wv[16];
    {
        const f32x2* wr2 = (const f32x2*)(W_hh + j * HH + kc * 32);
        #pragma unroll
        for (int i = 0; i < 8; ++i) {
            const int m = (i + 2 * kc) & 7;
            wv[2 * i]     = wr2[2 * m];
            wv[2 * i + 1] = wr2[2 * m + 1];
        }
    }
    f32x2 wi2 = ((const f32x2*)(W_ih + j * II))[kc];
    f32x2 bias2; bias2.x = 0.25f * (b_ih[j] + b_hh[j]); bias2.y = 0.0f;

    // Opaque pin: values become asm outputs -> NOT rematerializable.
    #pragma unroll
    for (int i = 0; i < 16; ++i) asm volatile("" : "+v"(wv[i]));
    asm volatile("" : "+v"(wi2), "+v"(bias2));

    const float* xg = x + (size_t)b * TT * II;

    if (tid < HH) {
        h_lds[0][tid] = h0[b * HH + tid];
        x_flat[tid]   = xg[tid];          // x for steps 0..15
    }
    __syncthreads();

    float xpre = 0.0f;
    int xoff = 2 * kc;                    // rolling index into x_flat (mod 256)

    for (int tb = 0; tb < TT; tb += 2) {
        #pragma unroll
        for (int half = 0; half < 2; ++half) {
            const int t  = tb + half;
            const int RB = half;          // read buffer (compile-time)

            if (tid < HH) {
                if ((t & 15) == 0) {
                    const int tn = t + 16;
                    xpre = (tn < TT) ? xg[tn * II + tid] : 0.0f;  // coalesced
                }
            }

            // ---- 8 broadcast ds_read_b128 of h, 17 packed FMAs ----
            const f32x2 xv = *(const f32x2*)&x_flat[xoff];
            f32x4 hv0 = *(const f32x4*)&h_lds[RB][kc * 32 + (((0 + 2*kc) & 7) << 2)];
            f32x4 hv1 = *(const f32x4*)&h_lds[RB][kc * 32 + (((1 + 2*kc) & 7) << 2)];
            f32x4 hv2 = *(const f32x4*)&h_lds[RB][kc * 32 + (((2 + 2*kc) & 7) << 2)];
            f32x4 hv3 = *(const f32x4*)&h_lds[RB][kc * 32 + (((3 + 2*kc) & 7) << 2)];
            f32x4 hv4 = *(const f32x4*)&h_lds[RB][kc * 32 + (((4 + 2*kc) & 7) << 2)];
            f32x4 hv5 = *(const f32x4*)&h_lds[RB][kc * 32 + (((5 + 2*kc) & 7) << 2)];
            f32x4 hv6 = *(const f32x4*)&h_lds[RB][kc * 32 + (((6 + 2*kc) & 7) << 2)];
            f32x4 hv7 = *(const f32x4*)&h_lds[RB][kc * 32 + (((7 + 2*kc) & 7) << 2)];

            f32x2 acc0, acc1, acc2, acc3;
            // acc0 = xv*wi2 + bias2 (asm, forces wi2/bias2 residency)
            asm("v_pk_fma_f32 %0, %1, %2, %3"
                : "=v"(acc0) : "v"(xv), "v"(wi2), "v"(bias2));

            #define HLO(v) __builtin_shufflevector(v, v, 0, 1)
            #define HHI(v) __builtin_shufflevector(v, v, 2, 3)
            #define PKFMA(acc, h2, wk) \
                asm("v_pk_fma_f32 %0, %1, %2, %0" : "+v"(acc) : "v"(h2), "v"(wv[wk]))

            // chain starters via compiler pk_mul (no literal-0 risk)
            acc1 = HLO(hv0) * wv[0];
            acc2 = HHI(hv0) * wv[1];
            acc3 = HLO(hv1) * wv[2];
            PKFMA(acc0, HHI(hv1), 3);
            PKFMA(acc1, HLO(hv2), 4);
            PKFMA(acc2, HHI(hv2), 5);
            PKFMA(acc3, HLO(hv3), 6);
            PKFMA(acc0, HHI(hv3), 7);
            PKFMA(acc1, HLO(hv4), 8);
            PKFMA(acc2, HHI(hv4), 9);
            PKFMA(acc3, HLO(hv5), 10);
            PKFMA(acc0, HHI(hv5), 11);
            PKFMA(acc1, HLO(hv6), 12);
            PKFMA(acc2, HHI(hv6), 13);
            PKFMA(acc3, HLO(hv7), 14);
            PKFMA(acc0, HHI(hv7), 15);
            #undef HLO
            #undef HHI
            #undef PKFMA

            const f32x2 ap = (acc0 + acc1) + (acc2 + acc3);  // v_pk_add_f32 x3
            const float acc = ap.x + ap.y;

            // cross-lane reduce over the 4 kc lanes (DPP, no barrier)
            const float s = quad_sum(acc);

            // tanh(s) = 1 - 2/(2^(2*log2e*s) + 1)
            const float e2 = __builtin_amdgcn_exp2f(s * 2.8853900817779268f);
            const float hn = 1.0f - 2.0f * __builtin_amdgcn_rcpf(e2 + 1.0f);

            if (kc == 0) h_lds[RB ^ 1][j] = hn;   // 16 distinct banks per wave

            if (tid < HH) {
                if ((t & 15) == 15) x_flat[(((t >> 4) + 1) & 1) * 16 * II + tid] = xpre;
            }

            xoff = (xoff + II) & (2 * 16 * II - 1);
            __syncthreads();   // ONE barrier per step
        }
    }

    // epilogue: final h is in h_lds[0] (t=2047 wrote RB^1 = 0)
    if (tid < HH) {
        const float hl = h_lds[0][tid];
        out[BB + b * HH + tid]           = hl;   // last_step_features
        out[BB + BB * HH + b * HH + tid] = hl;   // h_n
    }
    if (w == 0) {
        float s = h_lds[0][lane]      * W_head[lane]
                + h_lds[0][lane + 64] * W_head[lane + 64];
        #pragma unroll
        for (int off = 32; off > 0; off >>= 1) s += __shfl_down(s, off);
        if (lane == 0) out[b] = s + b_head[0];
    }
}

extern "C" void kernel_launch(void* const* d_in, const int* in_sizes, int n_in,
                              void* d_out, int out_size, void* d_ws, size_t ws_size,
                              hipStream_t stream) {
    const float* x      = (const float*)d_in[0];
    const float* h0     = (const float*)d_in[1];
    const float* W_ih   = (const float*)d_in[2];
    const float* W_hh   = (const float*)d_in[3];
    const float* b_ih   = (const float*)d_in[4];
    const float* b_hh   = (const float*)d_in[5];
    const float* W_head = (const float*)d_in[6];
    const float* b_head = (const float*)d_in[7];
    float* out = (float*)d_out;

    hipLaunchKernelGGL(rnn_fused4_kernel, dim3(BB), dim3(THREADS), 0, stream,
                       x, h0, W_ih, W_hh, b_ih, b_hh, W_head, b_head, out);
}